// Round 5
// baseline (390.401 us; speedup 1.0000x reference)
//
#include <hip/hip_runtime.h>
#include <hip/hip_bf16.h>

#define D_MODEL 128
#define SEQ_L   4096
#define BATCH   128
#define NSEG    8     // kmean segments

typedef float f4 __attribute__((ext_vector_type(4)));
typedef float f32x4 __attribute__((ext_vector_type(4)));
typedef short bf16x8 __attribute__((ext_vector_type(8)));

__device__ __forceinline__ unsigned short f2bf(float f) {
    union { float f; unsigned u; } v; v.f = f;
    unsigned r = v.u + 0x7FFFu + ((v.u >> 16) & 1u);
    return (unsigned short)(r >> 16);
}

// ---------------- kernel 1: partial mean over L  (+ folded Wc->bf16 cvt) ----------------
// grid (NSEG+1, 128), 512 threads. Blocks x<NSEG: partial sums. Block x==NSEG, y<8: cvt.
__global__ __launch_bounds__(512) void kmean(const float* __restrict__ x,
                                             float* __restrict__ part,
                                             const float* __restrict__ Wc,
                                             unsigned short* __restrict__ wcb) {
    if (blockIdx.x == NSEG) {
        if (blockIdx.y < 8) {
            int i = blockIdx.y * 512 + threadIdx.x;   // 4096 threads x 4 floats = 16384
            f4 v = reinterpret_cast<const f4*>(Wc)[i];
            ushort4 o;
            o.x = f2bf(v[0]); o.y = f2bf(v[1]); o.z = f2bf(v[2]); o.w = f2bf(v[3]);
            reinterpret_cast<ushort4*>(wcb)[i] = o;
        }
        return;
    }
    int seg = blockIdx.x, b = blockIdx.y;
    int t = threadIdx.x;
    int c4 = t & 31, ph = t >> 5;                 // ph: 0..15
    const f4* xb = reinterpret_cast<const f4*>(x + (size_t)b * SEQ_L * D_MODEL);
    int l0 = seg * (SEQ_L / NSEG);

    f4 a0 = {0.f,0.f,0.f,0.f}, a1 = a0, a2 = a0, a3 = a0;
    #pragma unroll
    for (int i = 0; i < 32; i += 4) {
        a0 += xb[(l0 + ph + (i + 0) * 16) * 32 + c4];
        a1 += xb[(l0 + ph + (i + 1) * 16) * 32 + c4];
        a2 += xb[(l0 + ph + (i + 2) * 16) * 32 + c4];
        a3 += xb[(l0 + ph + (i + 3) * 16) * 32 + c4];
    }
    f4 acc = (a0 + a1) + (a2 + a3);

    __shared__ f4 red[512];
    red[t] = acc;
    __syncthreads();
    if (t < 32) {
        f4 s = red[t];
        #pragma unroll
        for (int p = 1; p < 16; ++p) s += red[t + 32 * p];
        reinterpret_cast<f4*>(part + ((size_t)b * NSEG + seg) * D_MODEL)[t] = s;
    }
}

// ---------------- kernel 2: per-channel MLP + softmax -> w[3][128] ----------------
__global__ __launch_bounds__(128) void kweights(const float* __restrict__ part,
                                                const float* __restrict__ W1,
                                                const float* __restrict__ b1,
                                                const float* __restrict__ W2,
                                                const float* __restrict__ b2,
                                                float* __restrict__ w) {
    int c = threadIdx.x; // 0..127
    f4 mv[32];
    #pragma unroll
    for (int d4 = 0; d4 < 32; ++d4) mv[d4] = (f4){0.f, 0.f, 0.f, 0.f};
    for (int s = 0; s < NSEG; ++s) {
        const f4* ps = reinterpret_cast<const f4*>(part + ((size_t)c * NSEG + s) * D_MODEL);
        #pragma unroll
        for (int d4 = 0; d4 < 32; ++d4) mv[d4] += ps[d4];
    }
    #pragma unroll
    for (int d4 = 0; d4 < 32; ++d4) mv[d4] *= (1.0f / (float)SEQ_L);

    float h[32];
    #pragma unroll
    for (int j = 0; j < 32; ++j) {
        const f4* w1r = reinterpret_cast<const f4*>(W1 + j * 128);
        f4 s4 = {0.f, 0.f, 0.f, 0.f};
        #pragma unroll
        for (int d4 = 0; d4 < 32; ++d4) s4 += mv[d4] * w1r[d4];
        float s = s4[0] + s4[1] + s4[2] + s4[3] + b1[j];
        h[j] = 0.5f * s * (1.0f + erff(s * 0.70710678118654752f)); // exact gelu
    }
    float lg[3];
    float mx = -1e30f;
    #pragma unroll
    for (int k = 0; k < 3; ++k) {
        float s = b2[k];
        #pragma unroll
        for (int j = 0; j < 32; ++j) s += h[j] * W2[k * 32 + j];
        lg[k] = s;
        mx = fmaxf(mx, s);
    }
    float e[3], den = 0.f;
    #pragma unroll
    for (int k = 0; k < 3; ++k) { e[k] = __expf(lg[k] - mx); den += e[k]; }
    float inv = 1.0f / den;
    #pragma unroll
    for (int k = 0; k < 3; ++k) w[k * 128 + c] = e[k] * inv;
}

// ---------------- kernel 3: fused conv + matmul, NO LDS / NO BARRIERS ----------------
// Each lane builds its own MFMA B-fragments (y) in registers straight from global x.
// Wave = 64 tokens x 64 output channels, acc[4 groups][4 co-blocks].
template<bool GUARD>
__device__ __forceinline__ void tile64(const float* __restrict__ xb,
                                       const float* __restrict__ wv,
                                       const unsigned short* __restrict__ wcb,
                                       const float* __restrict__ bc,
                                       float* __restrict__ outb,
                                       int tokbase, int lane, int co0w) {
    const int r = lane & 15, q = lane >> 4;
    const int kb = q * 8;

    f32x4 acc[4][4];
    #pragma unroll
    for (int g = 0; g < 4; ++g)
        #pragma unroll
        for (int n = 0; n < 4; ++n) acc[g][n] = (f32x4){0.f, 0.f, 0.f, 0.f};

    #pragma unroll
    for (int kc = 0; kc < 4; ++kc) {
        const int off = kc * 32 + kb;

        // A-fragments (Wc) for this kc — 4 co-blocks, reloaded per kc to cap VGPR
        bf16x8 awc[4];
        #pragma unroll
        for (int n = 0; n < 4; ++n)
            awc[n] = *reinterpret_cast<const bf16x8*>(
                wcb + (size_t)(co0w + n * 16 + r) * D_MODEL + off);

        // conv tap weights for this lane's 8-channel slice (L1-hot, 1.5 KB buffer)
        f4 w0a = *reinterpret_cast<const f4*>(wv + off);
        f4 w0b = *reinterpret_cast<const f4*>(wv + off + 4);
        f4 w1a = *reinterpret_cast<const f4*>(wv + 128 + off);
        f4 w1b = *reinterpret_cast<const f4*>(wv + 128 + off + 4);
        f4 w2a = *reinterpret_cast<const f4*>(wv + 256 + off);
        f4 w2b = *reinterpret_cast<const f4*>(wv + 256 + off + 4);

        #pragma unroll
        for (int g = 0; g < 4; ++g) {
            int tok = tokbase + g * 16 + r;
            const float* xrow = xb + (size_t)tok * D_MODEL;
            const float* rm = xrow - D_MODEL;
            const float* rp = xrow + D_MODEL;
            bool gm = true, gp = true;
            if (GUARD) {
                gm = tok > 0; gp = tok < SEQ_L - 1;
                rm = gm ? rm : xrow;
                rp = gp ? rp : xrow;
            }
            f4 xma = *reinterpret_cast<const f4*>(rm + off);
            f4 xmb = *reinterpret_cast<const f4*>(rm + off + 4);
            f4 x0a = *reinterpret_cast<const f4*>(xrow + off);
            f4 x0b = *reinterpret_cast<const f4*>(xrow + off + 4);
            f4 xpa = *reinterpret_cast<const f4*>(rp + off);
            f4 xpb = *reinterpret_cast<const f4*>(rp + off + 4);
            if (GUARD) {
                f4 z = {0.f, 0.f, 0.f, 0.f};
                if (!gm) { xma = z; xmb = z; }
                if (!gp) { xpa = z; xpb = z; }
            }
            f4 y0 = xma * w0a + x0a * w1a + xpa * w2a;
            f4 y1 = xmb * w0b + x0b * w1b + xpb * w2b;
            // build B-fragment via well-defined ext-vector element inserts;
            // compiler fuses paired casts into v_cvt_pk_bf16_f32 itself (m240).
            bf16x8 pv;
            pv[0] = (short)f2bf(y0[0]);
            pv[1] = (short)f2bf(y0[1]);
            pv[2] = (short)f2bf(y0[2]);
            pv[3] = (short)f2bf(y0[3]);
            pv[4] = (short)f2bf(y1[0]);
            pv[5] = (short)f2bf(y1[1]);
            pv[6] = (short)f2bf(y1[2]);
            pv[7] = (short)f2bf(y1[3]);
            #pragma unroll
            for (int n = 0; n < 4; ++n)
                acc[g][n] = __builtin_amdgcn_mfma_f32_16x16x32_bf16(awc[n], pv, acc[g][n], 0, 0, 0);
        }
    }

    // epilogue: bias + float4 stores (co = co0w + n*16 + q*4 + reg, token = tokbase+g*16+r)
    #pragma unroll
    for (int g = 0; g < 4; ++g) {
        int tok = tokbase + g * 16 + r;
        float* orow = outb + (size_t)tok * D_MODEL + co0w + q * 4;
        #pragma unroll
        for (int n = 0; n < 4; ++n) {
            f4 bcv = *reinterpret_cast<const f4*>(bc + co0w + n * 16 + q * 4);
            *reinterpret_cast<f4*>(orow + n * 16) = acc[g][n] + bcv;
        }
    }
}

// grid (SEQ_L/128, BATCH), 256 threads = 4 waves: (w&1)=co-half, (w>>1)=token 64-chunk.
__global__ __launch_bounds__(256, 2) void kconv(const float* __restrict__ x,
                                                const float* __restrict__ wv,
                                                const unsigned short* __restrict__ wcb,
                                                const float* __restrict__ bc,
                                                float* __restrict__ out) {
    int t = threadIdx.x, lane = t & 63, w = t >> 6;
    int b = blockIdx.y;
    int tokbase = blockIdx.x * 128 + (w >> 1) * 64;
    int co0w = (w & 1) * 64;
    const float* xb = x + (size_t)b * SEQ_L * D_MODEL;
    float* outb = out + (size_t)b * SEQ_L * D_MODEL;
    if (blockIdx.x == 0 || blockIdx.x == (SEQ_L / 128) - 1)
        tile64<true>(xb, wv, wcb, bc, outb, tokbase, lane, co0w);
    else
        tile64<false>(xb, wv, wcb, bc, outb, tokbase, lane, co0w);
}

extern "C" void kernel_launch(void* const* d_in, const int* in_sizes, int n_in,
                              void* d_out, int out_size, void* d_ws, size_t ws_size,
                              hipStream_t stream) {
    const float* x  = (const float*)d_in[0];
    const float* W1 = (const float*)d_in[1];
    const float* b1 = (const float*)d_in[2];
    const float* W2 = (const float*)d_in[3];
    const float* b2 = (const float*)d_in[4];
    const float* Wc = (const float*)d_in[5];
    const float* bc = (const float*)d_in[6];
    float* out = (float*)d_out;

    char* ws = (char*)d_ws;
    float* part = (float*)ws;                               // 128*8*128*4 = 512 KB
    float* w    = (float*)(ws + 524288);                    // 3*128*4 = 1.5 KB
    unsigned short* wcb = (unsigned short*)(ws + 526336);   // 128*128*2 = 32 KB

    kmean<<<dim3(NSEG + 1, BATCH), 512, 0, stream>>>(x, part, Wc, wcb);
    kweights<<<1, 128, 0, stream>>>(part, W1, b1, W2, b2, w);
    kconv<<<dim3(SEQ_L / 128, BATCH), 256, 0, stream>>>(x, w, wcb, bc, out);
}

// Round 6
// 235.726 us; speedup vs baseline: 1.6562x; 1.6562x over previous
//
#include <hip/hip_runtime.h>
#include <hip/hip_bf16.h>

#define D_MODEL 128
#define SEQ_L   4096
#define BATCH   128
#define NSEG    8     // kmean segments

typedef float f4 __attribute__((ext_vector_type(4)));
typedef float f32x4 __attribute__((ext_vector_type(4)));
typedef short bf16x8 __attribute__((ext_vector_type(8)));

__device__ __forceinline__ unsigned short f2bf(float f) {
    union { float f; unsigned u; } v; v.f = f;
    unsigned r = v.u + 0x7FFFu + ((v.u >> 16) & 1u);
    return (unsigned short)(r >> 16);
}

// ---------------- kernel 1: partial mean over L  (+ folded Wc->bf16 cvt) ----------------
// grid (NSEG+1, 128), 512 threads. Blocks x<NSEG: partial sums. Block x==NSEG, y<8: cvt.
__global__ __launch_bounds__(512) void kmean(const float* __restrict__ x,
                                             float* __restrict__ part,
                                             const float* __restrict__ Wc,
                                             unsigned short* __restrict__ wcb) {
    if (blockIdx.x == NSEG) {
        if (blockIdx.y < 8) {
            int i = blockIdx.y * 512 + threadIdx.x;   // 4096 threads x 4 floats = 16384
            f4 v = reinterpret_cast<const f4*>(Wc)[i];
            ushort4 o;
            o.x = f2bf(v[0]); o.y = f2bf(v[1]); o.z = f2bf(v[2]); o.w = f2bf(v[3]);
            reinterpret_cast<ushort4*>(wcb)[i] = o;
        }
        return;
    }
    int seg = blockIdx.x, b = blockIdx.y;
    int t = threadIdx.x;
    int c4 = t & 31, ph = t >> 5;                 // ph: 0..15
    const f4* xb = reinterpret_cast<const f4*>(x + (size_t)b * SEQ_L * D_MODEL);
    int l0 = seg * (SEQ_L / NSEG);

    f4 a0 = {0.f,0.f,0.f,0.f}, a1 = a0, a2 = a0, a3 = a0;
    #pragma unroll
    for (int i = 0; i < 32; i += 4) {
        a0 += xb[(l0 + ph + (i + 0) * 16) * 32 + c4];
        a1 += xb[(l0 + ph + (i + 1) * 16) * 32 + c4];
        a2 += xb[(l0 + ph + (i + 2) * 16) * 32 + c4];
        a3 += xb[(l0 + ph + (i + 3) * 16) * 32 + c4];
    }
    f4 acc = (a0 + a1) + (a2 + a3);

    __shared__ f4 red[512];
    red[t] = acc;
    __syncthreads();
    if (t < 32) {
        f4 s = red[t];
        #pragma unroll
        for (int p = 1; p < 16; ++p) s += red[t + 32 * p];
        reinterpret_cast<f4*>(part + ((size_t)b * NSEG + seg) * D_MODEL)[t] = s;
    }
}

// ---------------- kernel 2: per-channel MLP + softmax -> w[3][128] ----------------
__global__ __launch_bounds__(128) void kweights(const float* __restrict__ part,
                                                const float* __restrict__ W1,
                                                const float* __restrict__ b1,
                                                const float* __restrict__ W2,
                                                const float* __restrict__ b2,
                                                float* __restrict__ w) {
    int c = threadIdx.x; // 0..127
    f4 mv[32];
    #pragma unroll
    for (int d4 = 0; d4 < 32; ++d4) mv[d4] = (f4){0.f, 0.f, 0.f, 0.f};
    for (int s = 0; s < NSEG; ++s) {
        const f4* ps = reinterpret_cast<const f4*>(part + ((size_t)c * NSEG + s) * D_MODEL);
        #pragma unroll
        for (int d4 = 0; d4 < 32; ++d4) mv[d4] += ps[d4];
    }
    #pragma unroll
    for (int d4 = 0; d4 < 32; ++d4) mv[d4] *= (1.0f / (float)SEQ_L);

    float h[32];
    #pragma unroll
    for (int j = 0; j < 32; ++j) {
        const f4* w1r = reinterpret_cast<const f4*>(W1 + j * 128);
        f4 s4 = {0.f, 0.f, 0.f, 0.f};
        #pragma unroll
        for (int d4 = 0; d4 < 32; ++d4) s4 += mv[d4] * w1r[d4];
        float s = s4[0] + s4[1] + s4[2] + s4[3] + b1[j];
        h[j] = 0.5f * s * (1.0f + erff(s * 0.70710678118654752f)); // exact gelu
    }
    float lg[3];
    float mx = -1e30f;
    #pragma unroll
    for (int k = 0; k < 3; ++k) {
        float s = b2[k];
        #pragma unroll
        for (int j = 0; j < 32; ++j) s += h[j] * W2[k * 32 + j];
        lg[k] = s;
        mx = fmaxf(mx, s);
    }
    float e[3], den = 0.f;
    #pragma unroll
    for (int k = 0; k < 3; ++k) { e[k] = __expf(lg[k] - mx); den += e[k]; }
    float inv = 1.0f / den;
    #pragma unroll
    for (int k = 0; k < 3; ++k) w[k * 128 + c] = e[k] * inv;
}

// ---------------- kernel 3: fused conv + matmul, pipelined LDS double-buffer ----------------
// Block = 256 tokens as 4 half-tiles of 64. Next half's global loads are issued
// BETWEEN the lds-write barrier and the MFMA phase (T14 async-stage): they fly
// under MFMA+stores; the vmcnt wait lands at the next iteration's y-compute.
template<bool GUARD>
__device__ __forceinline__ void load6(const float* __restrict__ xb, int gr0, int c4, f4 R[6]) {
    #pragma unroll
    for (int j = 0; j < 6; ++j) {
        int gr = gr0 + j;
        if (GUARD) {
            bool ok = (gr >= 0) && (gr < SEQ_L);
            int grc = ok ? gr : 0;
            f4 v = reinterpret_cast<const f4*>(xb + (size_t)grc * D_MODEL)[c4];
            f4 z = {0.f, 0.f, 0.f, 0.f};
            R[j] = ok ? v : z;
        } else {
            R[j] = reinterpret_cast<const f4*>(xb + (size_t)gr * D_MODEL)[c4];
        }
    }
}

// grid (SEQ_L/256, BATCH), 512 threads = 8 waves; wave w -> co block w*16.
__global__ __launch_bounds__(512, 2) void kconv(const float* __restrict__ x,
                                                const float* __restrict__ wv,
                                                const unsigned short* __restrict__ wcb,
                                                const float* __restrict__ bc,
                                                float* __restrict__ out) {
    __shared__ __align__(16) unsigned short y_lds[2][64][132];

    int t = threadIdx.x;
    int b = blockIdx.y;
    int base = blockIdx.x * 256;
    const float* xb = x + (size_t)b * SEQ_L * D_MODEL;
    float* outb = out + (size_t)b * SEQ_L * D_MODEL;

    int c4 = t & 31, rg = t >> 5;            // rg: 0..15, owns rows rg*4..rg*4+3 of half
    int lane = t & 63, wid = t >> 6;
    int r = lane & 15, q = lane >> 4, kb = q * 8;
    int co0 = wid * 16;

    // conv taps for this thread's channel quad
    f4 w0 = reinterpret_cast<const f4*>(wv)[c4];
    f4 w1 = reinterpret_cast<const f4*>(wv + 128)[c4];
    f4 w2 = reinterpret_cast<const f4*>(wv + 256)[c4];

    // Wc A-fragments, loaded once (L2-hot)
    bf16x8 awc[4];
    #pragma unroll
    for (int kc = 0; kc < 4; ++kc)
        awc[kc] = *reinterpret_cast<const bf16x8*>(wcb + (size_t)(co0 + r) * D_MODEL + kc * 32 + kb);

    f4 bcv = *reinterpret_cast<const f4*>(bc + co0 + q * 4);

    // prologue: load half 0
    f4 R[6];
    if (base == 0) load6<true>(xb, base + rg * 4 - 1, c4, R);
    else           load6<false>(xb, base + rg * 4 - 1, c4, R);

    #pragma unroll
    for (int i = 0; i < 4; ++i) {
        int buf = i & 1;
        // y-compute (waits this half's loads) + LDS write
        #pragma unroll
        for (int j = 0; j < 4; ++j) {
            f4 y = R[j] * w0 + R[j + 1] * w1 + R[j + 2] * w2;
            ushort4 yb;
            yb.x = f2bf(y[0]); yb.y = f2bf(y[1]); yb.z = f2bf(y[2]); yb.w = f2bf(y[3]);
            *reinterpret_cast<ushort4*>(&y_lds[buf][rg * 4 + j][c4 * 4]) = yb;
        }
        // issue NEXT half's loads (in flight under MFMA+stores)
        if (i < 3) {
            int ntok0 = base + (i + 1) * 64;
            if (ntok0 + 64 == SEQ_L) load6<true>(xb, ntok0 + rg * 4 - 1, c4, R);
            else                     load6<false>(xb, ntok0 + rg * 4 - 1, c4, R);
        }
        __syncthreads();   // y_lds[buf] visible

        // MFMA: wave = 64 tokens x 16 co
        f32x4 acc[4];
        #pragma unroll
        for (int g = 0; g < 4; ++g) acc[g] = (f32x4){0.f, 0.f, 0.f, 0.f};
        #pragma unroll
        for (int g = 0; g < 4; ++g)
            #pragma unroll
            for (int kc = 0; kc < 4; ++kc) {
                bf16x8 bv = *reinterpret_cast<const bf16x8*>(&y_lds[buf][g * 16 + r][kc * 32 + kb]);
                acc[g] = __builtin_amdgcn_mfma_f32_16x16x32_bf16(awc[kc], bv, acc[g], 0, 0, 0);
            }

        // epilogue: token = base+i*64+g*16+r (col=lane&15), co = co0+q*4+reg (row)
        int tokt = base + i * 64;
        #pragma unroll
        for (int g = 0; g < 4; ++g) {
            int tok = tokt + g * 16 + r;
            *reinterpret_cast<f4*>(outb + (size_t)tok * D_MODEL + co0 + q * 4) = acc[g] + bcv;
        }
        __syncthreads();   // all waves done reading y_lds[buf] before it's rewritten
    }
}

extern "C" void kernel_launch(void* const* d_in, const int* in_sizes, int n_in,
                              void* d_out, int out_size, void* d_ws, size_t ws_size,
                              hipStream_t stream) {
    const float* x  = (const float*)d_in[0];
    const float* W1 = (const float*)d_in[1];
    const float* b1 = (const float*)d_in[2];
    const float* W2 = (const float*)d_in[3];
    const float* b2 = (const float*)d_in[4];
    const float* Wc = (const float*)d_in[5];
    const float* bc = (const float*)d_in[6];
    float* out = (float*)d_out;

    char* ws = (char*)d_ws;
    float* part = (float*)ws;                               // 128*8*128*4 = 512 KB
    float* w    = (float*)(ws + 524288);                    // 3*128*4 = 1.5 KB
    unsigned short* wcb = (unsigned short*)(ws + 526336);   // 128*128*2 = 32 KB

    kmean<<<dim3(NSEG + 1, BATCH), 512, 0, stream>>>(x, part, Wc, wcb);
    kweights<<<1, 128, 0, stream>>>(part, W1, b1, W2, b2, w);
    kconv<<<dim3(SEQ_L / 256, BATCH), 512, 0, stream>>>(x, w, wcb, bc, out);
}